// Round 9
// baseline (296.491 us; speedup 1.0000x reference)
//
#include <hip/hip_runtime.h>
#include <math.h>

#define B_N   8192
#define D_K   256
#define NGENE 200
#define MAXN  512
#define CROWS 128   // genes with n<=CROWS cache rows in LDS (padded stride 33)

typedef short  bf16x8 __attribute__((ext_vector_type(8)));
typedef float  f32x4  __attribute__((ext_vector_type(4)));

// ---- workspace layout (bytes), total 4,757,504 (proven size) ----
#define OFF_FNBF    0u          // 8192*256*2 = 4194304
#define OFF_LPART   4194304u    // f32 [16][8192] = 524288
#define OFF_HIST    4718592u    // 256*4
#define OFF_OFFS    4719616u    // 256*4
#define OFF_SORTED  4720640u    // 8192*4
#define OFF_CROSSP  4753408u    // 512*4
#define OFF_WITHINP 4755456u    // 256*4
#define OFF_CCORR   4756480u    // 256*4

__device__ __forceinline__ unsigned short f2bf(float f) {
    unsigned int u = __float_as_uint(f);
    unsigned int r = u + 0x7fffu + ((u >> 16) & 1u);
    return (unsigned short)(r >> 16);
}
__device__ __forceinline__ float bf2f_lo(unsigned int u) { return __uint_as_float(u << 16); }
__device__ __forceinline__ float bf2f_hi(unsigned int u) { return __uint_as_float(u & 0xffff0000u); }

// ---- kernel 1: normalize (blocks 0..2047) + hist/prefix/scatter (block 2048) ----
__global__ __launch_bounds__(256) void k_np(const float* __restrict__ feat,
                                            const int* __restrict__ lab,
                                            unsigned short* __restrict__ fnbf,
                                            int* __restrict__ hist,
                                            int* __restrict__ offs,
                                            int* __restrict__ sorted) {
    if (blockIdx.x < 2048) {
        int wave = threadIdx.x >> 6, lane = threadIdx.x & 63;
        int row  = blockIdx.x * 4 + wave;
        const float4* src = reinterpret_cast<const float4*>(feat + (size_t)row * D_K);
        float4 v = src[lane];
        float ss = v.x * v.x + v.y * v.y + v.z * v.z + v.w * v.w;
#pragma unroll
        for (int m = 1; m < 64; m <<= 1) ss += __shfl_xor(ss, m);
        float rn = 1.0f / sqrtf(ss);
        ushort4 o;
        o.x = f2bf(v.x * rn); o.y = f2bf(v.y * rn);
        o.z = f2bf(v.z * rn); o.w = f2bf(v.w * rn);
        reinterpret_cast<ushort4*>(fnbf + (size_t)row * D_K)[lane] = o;
        return;
    }
    __shared__ int sh_hist[256], sh_scan[256], sh_cur[256];
    int t = threadIdx.x;
    sh_hist[t] = 0;
    __syncthreads();
    for (int i = t; i < B_N; i += 256) {
        int lb = lab[i];
        if (lb >= 0 && lb < NGENE) atomicAdd(&sh_hist[lb], 1);
    }
    __syncthreads();
    int v = sh_hist[t];
    sh_scan[t] = v;
    __syncthreads();
#pragma unroll
    for (int d = 1; d < 256; d <<= 1) {
        int x = (t >= d) ? sh_scan[t - d] : 0;
        __syncthreads();
        sh_scan[t] += x;
        __syncthreads();
    }
    int excl = sh_scan[t] - v;
    sh_cur[t] = excl;
    if (t < NGENE) { hist[t] = v; offs[t] = excl; }
    __syncthreads();
    for (int i = t; i < B_N; i += 256) {
        int lb = lab[i];
        if (lb >= 0 && lb < NGENE) {
            int pos = atomicAdd(&sh_cur[lb], 1);
            sorted[pos] = i;
        }
    }
}

// asm-pinned A-fragment loads (compiler cannot rematerialize or sink)
#define GLOAD8(arr, vo) do {                                                                   \
    asm volatile("global_load_dwordx4 %0, %1, %2 offset:0"   : "=v"(arr[0]) : "v"(vo), "s"(fb)); \
    asm volatile("global_load_dwordx4 %0, %1, %2 offset:64"  : "=v"(arr[1]) : "v"(vo), "s"(fb)); \
    asm volatile("global_load_dwordx4 %0, %1, %2 offset:128" : "=v"(arr[2]) : "v"(vo), "s"(fb)); \
    asm volatile("global_load_dwordx4 %0, %1, %2 offset:192" : "=v"(arr[3]) : "v"(vo), "s"(fb)); \
    asm volatile("global_load_dwordx4 %0, %1, %2 offset:256" : "=v"(arr[4]) : "v"(vo), "s"(fb)); \
    asm volatile("global_load_dwordx4 %0, %1, %2 offset:320" : "=v"(arr[5]) : "v"(vo), "s"(fb)); \
    asm volatile("global_load_dwordx4 %0, %1, %2 offset:384" : "=v"(arr[6]) : "v"(vo), "s"(fb)); \
    asm volatile("global_load_dwordx4 %0, %1, %2 offset:448" : "=v"(arr[7]) : "v"(vo), "s"(fb)); \
} while (0)

// async global->LDS, 16B per lane, zero VGPR result cost
#define GL_LDS16(gp, lp)                                                          \
    __builtin_amdgcn_global_load_lds(                                             \
        (const __attribute__((address_space(1))) unsigned int*)(gp),              \
        (__attribute__((address_space(3))) unsigned int*)(lp), 16, 0, 0)

#define Z4 ((f32x4){0.f, 0.f, 0.f, 0.f})
#define MFMA(A, B, C) __builtin_amdgcn_mfma_f32_16x16x32_bf16(A, B, C, 0, 0, 0)

#define EPI(AC, LS, CS) do {                                    \
    _Pragma("unroll")                                           \
    for (int r = 0; r < 4; ++r) {                               \
        float av = AC[r];                                       \
        LS[r] += __expf(2.0f * av);                             \
        CS += fmaxf(av - 0.05f, 0.f);                           \
    }                                                           \
} while (0)

#define STAGE(BUF) do {                    \
    GL_LDS16(g0, smem_c + (BUF) + st0);    \
    GL_LDS16(g1, smem_c + (BUF) + st1);    \
    GL_LDS16(g2, smem_c + (BUF) + st2);    \
    GL_LDS16(g3, smem_c + (BUF) + st3);    \
    g0 += 16384; g1 += 16384; g2 += 16384; g3 += 16384; \
} while (0)

#define WAIT_VM(n) do { asm volatile("s_waitcnt vmcnt(" #n ")" ::: "memory"); \
                        __builtin_amdgcn_sched_barrier(0); } while (0)

// ---- kernel 2: fused pairwise pass, ring-4 LDS staging with counted vmcnt ----
__global__ __launch_bounds__(256, 2) void k_pairwise(const unsigned short* __restrict__ fnbf,
                                                     float* __restrict__ l_part,
                                                     float* __restrict__ cross_part) {
    __shared__ __align__(16) char smem_c[65536];   // 4 x 16KB B tile ring

    int wave = threadIdx.x >> 6, lane = threadIdx.x & 63;
    int g16 = lane >> 4, l16 = lane & 15;
    int l7 = l16 & 7;
    int rg = blockIdx.x, cwin = blockIdx.y;
    int r0 = rg * 256 + wave * 64;
    const unsigned short* fb = fnbf;

    // A fragments pinned: 4 row-tiles x 8 k-slices = 128 VGPRs
    bf16x8 a0[8], a1[8], a2[8], a3[8];
    unsigned voa = (unsigned)(r0 + l16) * 512u + (unsigned)g16 * 16u;
    GLOAD8(a0, voa); voa += 16u * 512u;
    GLOAD8(a1, voa); voa += 16u * 512u;
    GLOAD8(a2, voa); voa += 16u * 512u;
    GLOAD8(a3, voa);

    // staging source addresses: LDS slot f = col*32 + s receives global chunk
    // c = s ^ (col&7). 4 issues/wave, 1KB each: f = wave*256 + q*64 + lane.
    const char* gwin = (const char*)fnbf + (size_t)cwin * 262144u;  // col-window base
    const char *g0, *g1, *g2, *g3;
    {
        int f0 = wave * 256 + lane;
        int f1 = f0 + 64, f2 = f0 + 128, f3 = f0 + 192;
        int c0 = f0 >> 5, c1 = f1 >> 5, c2 = f2 >> 5, c3 = f3 >> 5;
        g0 = gwin + c0 * 512 + ((f0 & 31) ^ (c0 & 7)) * 16;
        g1 = gwin + c1 * 512 + ((f1 & 31) ^ (c1 & 7)) * 16;
        g2 = gwin + c2 * 512 + ((f2 & 31) ^ (c2 & 7)) * 16;
        g3 = gwin + c3 * 512 + ((f3 & 31) ^ (c3 & 7)) * 16;
    }
    unsigned st0 = wave * 4096u, st1 = st0 + 1024u,
             st2 = st0 + 2048u, st3 = st0 + 3072u;

    // prologue: stage tiles 0,1,2 into bufs 0,1,2; drain A loads (leave 12 staging)
    STAGE(0u);
    STAGE(16384u);
    STAGE(32768u);
    WAIT_VM(12);

    float lsum[4][4] = {};
    float cs0 = 0.f, cs1 = 0.f, cs2 = 0.f, cs3 = 0.f;
    int vb = l16 * 512;

#pragma unroll 1
    for (int st = 0; st < 16; ++st) {
        // tile st was staged 3 steps ago -> this wait is (nearly) free
        if (st < 14)      { WAIT_VM(8); }
        else if (st == 14){ WAIT_VM(4); }
        else              { WAIT_VM(0); }
        __syncthreads();   // publish tile st; frees buf[(st+3)&3] for restage

        if (st < 13) {
            unsigned nb = ((unsigned)(st + 3) & 3u) << 14;
            STAGE(nb);
        }

        const char* base = smem_c + (((unsigned)st & 3u) << 14);
        f32x4 acA0 = Z4, acA1 = Z4, acA2 = Z4, acA3 = Z4;
        f32x4 acB0 = Z4, acB1 = Z4, acB2 = Z4, acB3 = Z4;
#pragma unroll
        for (int ks = 0; ks < 8; ++ks) {
            // chunk (ks*4 + g16) of col l16 lives at slot ((ks*4+g16) ^ l7)
            const char* p = base + (unsigned)(vb + ((((ks << 2) | g16) ^ l7) << 4));
            bf16x8 bv0 = *(const bf16x8*)p;
            bf16x8 bv1 = *(const bf16x8*)(p + 8192);
            acA0 = MFMA(a0[ks], bv0, acA0);
            acA1 = MFMA(a1[ks], bv0, acA1);
            acA2 = MFMA(a2[ks], bv0, acA2);
            acA3 = MFMA(a3[ks], bv0, acA3);
            acB0 = MFMA(a0[ks], bv1, acB0);
            acB1 = MFMA(a1[ks], bv1, acB1);
            acB2 = MFMA(a2[ks], bv1, acB2);
            acB3 = MFMA(a3[ks], bv1, acB3);
        }
        EPI(acA0, lsum[0], cs0); EPI(acA1, lsum[1], cs1);
        EPI(acA2, lsum[2], cs2); EPI(acA3, lsum[3], cs3);
        EPI(acB0, lsum[0], cs0); EPI(acB1, lsum[1], cs1);
        EPI(acB2, lsum[2], cs2); EPI(acB3, lsum[3], cs3);
    }

    // reduce exp-sums across the 16 lanes sharing each output row
#pragma unroll
    for (int t = 0; t < 4; ++t)
#pragma unroll
        for (int r = 0; r < 4; ++r) {
            float v = lsum[t][r];
            v += __shfl_xor(v, 1); v += __shfl_xor(v, 2);
            v += __shfl_xor(v, 4); v += __shfl_xor(v, 8);
            if (l16 == 0)
                l_part[(size_t)cwin * B_N + r0 + t * 16 + g16 * 4 + r] = v;
        }

    // block-reduce half-relu sum
    float c = (cs0 + cs1) + (cs2 + cs3);
#pragma unroll
    for (int m = 1; m < 64; m <<= 1) c += __shfl_xor(c, m);
    __shared__ float shc[4];
    if (lane == 0) shc[wave] = c;
    __syncthreads();
    if (threadIdx.x == 0)
        cross_part[cwin * 32 + rg] = shc[0] + shc[1] + shc[2] + shc[3];
}

// 16-lane partial dot of two uint4 chunks (8 bf16 each)
__device__ __forceinline__ float dot_part(uint4 a, uint4 b) {
    float d = 0.f;
    d = fmaf(bf2f_lo(a.x), bf2f_lo(b.x), d);
    d = fmaf(bf2f_hi(a.x), bf2f_hi(b.x), d);
    d = fmaf(bf2f_lo(a.y), bf2f_lo(b.y), d);
    d = fmaf(bf2f_hi(a.y), bf2f_hi(b.y), d);
    d = fmaf(bf2f_lo(a.z), bf2f_lo(b.z), d);
    d = fmaf(bf2f_hi(a.z), bf2f_hi(b.z), d);
    d = fmaf(bf2f_lo(a.w), bf2f_lo(b.w), d);
    d = fmaf(bf2f_hi(a.w), bf2f_hi(b.w), d);
    return d;
}
__device__ __forceinline__ float red16(float d) {
    d += __shfl_xor(d, 1); d += __shfl_xor(d, 2);
    d += __shfl_xor(d, 4); d += __shfl_xor(d, 8);
    return d;
}

// ---- kernel 3: per-gene corrections + lse + within-gene loss ----
// 16-lane cooperative dots; LDS row cache padded to stride 33 (bank-rotating);
// no atomics anywhere (row-parallel exp-subtract) -> deterministic.
__global__ __launch_bounds__(256) void k_within(const unsigned short* __restrict__ fnbf,
                                                const int* __restrict__ hist,
                                                const int* __restrict__ offs,
                                                const int* __restrict__ sorted,
                                                const float* __restrict__ l_part,
                                                float* __restrict__ within_part,
                                                float* __restrict__ cross_corr) {
    int g = blockIdx.x;
    int n = hist[g], start = offs[g];
    int t = threadIdx.x;
    int gid = t >> 4, l16 = t & 15;
    __shared__ int   rid[MAXN];
    __shared__ float rexp[MAXN];
    __shared__ float slse[MAXN];
    __shared__ float red[256];
    __shared__ __align__(16) uint4 srows[CROWS * 33];   // 67.6KB padded row cache

    const uint4* fu = reinterpret_cast<const uint4*>(fnbf);
    bool cached = (n <= CROWS);

    for (int idx = t; idx < n; idx += 256) rid[idx] = sorted[start + idx];
    __syncthreads();
    if (cached) {
        for (int c = t; c < n * 32; c += 256)
            srows[(c >> 5) * 33 + (c & 31)] = fu[(size_t)rid[c >> 5] * 32 + (c & 31)];
        __syncthreads();
    }

    float ccor = 0.f;   // identical across the 16 lanes of a group; /16 at reduce

    // row-parallel: rexp[idx] = raw - sum_{j in gene} exp(2*dot(idx,j))  (incl. diag)
    // ccor += relu over all ordered same-gene pairs + diagonal (counted once each)
    for (int idx = gid; idx < n; idx += 16) {
        uint4 a0, a1;
        if (cached) { a0 = srows[idx * 33 + l16]; a1 = srows[idx * 33 + 16 + l16]; }
        else {
            const uint4* pa = fu + (size_t)rid[idx] * 32;
            a0 = pa[l16]; a1 = pa[16 + l16];
        }
        float esum = 0.f;
        for (int j = 0; j < n; ++j) {
            uint4 b0, b1;
            if (cached) { b0 = srows[j * 33 + l16]; b1 = srows[j * 33 + 16 + l16]; }
            else {
                const uint4* pb = fu + (size_t)rid[j] * 32;
                b0 = pb[l16]; b1 = pb[16 + l16];
            }
            float d = red16(dot_part(a0, b0) + dot_part(a1, b1));
            float s = 2.0f * d;
            esum += __expf(s);
            ccor += fmaxf(s - 0.1f, 0.f);
        }
        // raw: 16 partial sums, one chunk per lane, reduced across the group
        float raw = red16(l_part[(size_t)l16 * B_N + rid[idx]]);
        if (l16 == 0) rexp[idx] = raw - esum;
    }
    __syncthreads();

    for (int idx = t; idx < n; idx += 256)
        slse[idx] = __logf(rexp[idx]);
    __syncthreads();

    // pair-parallel softplus: group per pair, anchor = smaller row index
    float wsum = 0.f;   // lane0-only accumulation
    int P = n * (n - 1) / 2;
    for (int p = gid; p < P; p += 16) {
        int aa = 0, pp = p, span = n - 1;
        while (pp >= span) { pp -= span; ++aa; --span; }
        int bb = aa + 1 + pp;
        uint4 a0, a1, b0, b1;
        if (cached) {
            a0 = srows[aa * 33 + l16]; a1 = srows[aa * 33 + 16 + l16];
            b0 = srows[bb * 33 + l16]; b1 = srows[bb * 33 + 16 + l16];
        } else {
            const uint4* pa = fu + (size_t)rid[aa] * 32;
            const uint4* pb = fu + (size_t)rid[bb] * 32;
            a0 = pa[l16]; a1 = pa[16 + l16];
            b0 = pb[l16]; b1 = pb[16 + l16];
        }
        float d = red16(dot_part(a0, b0) + dot_part(a1, b1));
        int ia = rid[aa], ib = rid[bb];
        int ai = (ia < ib) ? aa : bb;
        float x = slse[ai] - 2.0f * d;
        if (l16 == 0)
            wsum += fmaxf(x, 0.f) + log1pf(__expf(-fabsf(x)));
    }

    red[t] = wsum;
    __syncthreads();
#pragma unroll
    for (int d2 = 128; d2 > 0; d2 >>= 1) {
        if (t < d2) red[t] += red[t + d2];
        __syncthreads();
    }
    if (t == 0) within_part[g] = red[0];
    __syncthreads();
    red[t] = ccor;
    __syncthreads();
#pragma unroll
    for (int d2 = 128; d2 > 0; d2 >>= 1) {
        if (t < d2) red[t] += red[t + d2];
        __syncthreads();
    }
    if (t == 0) cross_corr[g] = red[0] * 0.0625f;   // /16 (lanes duplicated)
}

// ---- kernel 4: final reduction + outputs ----
__global__ __launch_bounds__(256) void k_finalize(const float* __restrict__ cross_part,
                                                  const float* __restrict__ within_part,
                                                  const float* __restrict__ cross_corr,
                                                  const int* __restrict__ hist,
                                                  float* __restrict__ out) {
    __shared__ float shc[256];
    __shared__ float shw[256];
    __shared__ float shk[256];
    __shared__ long long shs[256];
    int t = threadIdx.x;
    float cs = 0.f;
    for (int i = t; i < 512; i += 256) cs += cross_part[i];
    float wv = 0.f, cc = 0.f;
    long long s2 = 0;
    if (t < NGENE) {
        wv = within_part[t];
        cc = cross_corr[t];
        long long h = hist[t];
        s2 = h * h;
    }
    shc[t] = cs; shw[t] = wv; shk[t] = cc; shs[t] = s2;
    __syncthreads();
#pragma unroll
    for (int d = 128; d > 0; d >>= 1) {
        if (t < d) {
            shc[t] += shc[t + d]; shw[t] += shw[t + d];
            shk[t] += shk[t + d]; shs[t] += shs[t + d];
        }
        __syncthreads();
    }
    if (t == 0) {
        long long S  = shs[0];
        long long nw = S - (long long)B_N;
        long long nc = (long long)B_N * (long long)B_N - S;
        float cross_total = 2.0f * shc[0] - shk[0];   // csum was half-relu units
        float cross_loss = (nc > 0) ? (cross_total / (float)(nc > 1 ? nc : 1)) : 0.f;
        float within     = shw[0];
        out[0] = within + 0.5f * cross_loss;
        out[1] = within;
        out[2] = cross_loss;
        out[3] = (float)nw;
        out[4] = (float)nc;
    }
}

extern "C" void kernel_launch(void* const* d_in, const int* in_sizes, int n_in,
                              void* d_out, int out_size, void* d_ws, size_t ws_size,
                              hipStream_t stream) {
    const float* feat = (const float*)d_in[0];
    const int*   lab  = (const int*)d_in[1];
    float* out = (float*)d_out;
    char* ws = (char*)d_ws;

    unsigned short* fnbf = (unsigned short*)(ws + OFF_FNBF);
    float* l_part        = (float*)(ws + OFF_LPART);
    int*   hist          = (int*)(ws + OFF_HIST);
    int*   offs          = (int*)(ws + OFF_OFFS);
    int*   sorted        = (int*)(ws + OFF_SORTED);
    float* cross_part    = (float*)(ws + OFF_CROSSP);
    float* within_part   = (float*)(ws + OFF_WITHINP);
    float* cross_corr    = (float*)(ws + OFF_CCORR);

    k_np<<<2049, 256, 0, stream>>>(feat, lab, fnbf, hist, offs, sorted);
    k_pairwise<<<dim3(32, 16), 256, 0, stream>>>(fnbf, l_part, cross_part);
    k_within<<<NGENE, 256, 0, stream>>>(fnbf, hist, offs, sorted, l_part, within_part, cross_corr);
    k_finalize<<<1, 256, 0, stream>>>(cross_part, within_part, cross_corr, hist, out);
}

// Round 10
// 94.849 us; speedup vs baseline: 3.1259x; 3.1259x over previous
//
#include <hip/hip_runtime.h>
#include <math.h>

#define B_N   8192
#define D_K   256
#define NGENE 200
#define MAXN  512

typedef short  bf16x8 __attribute__((ext_vector_type(8)));
typedef float  f32x4  __attribute__((ext_vector_type(4)));

// ---- workspace layout (bytes), total 4,757,504 (proven size) ----
#define OFF_FNBF    0u          // 8192*256*2 = 4194304
#define OFF_LPART   4194304u    // f32 [16][8192] = 524288
#define OFF_HIST    4718592u    // 256*4
#define OFF_OFFS    4719616u    // 256*4
#define OFF_SORTED  4720640u    // 8192*4
#define OFF_CROSSP  4753408u    // 512*4
#define OFF_WITHINP 4755456u    // 256*4
#define OFF_CCORR   4756480u    // 256*4

__device__ __forceinline__ unsigned short f2bf(float f) {
    unsigned int u = __float_as_uint(f);
    unsigned int r = u + 0x7fffu + ((u >> 16) & 1u);
    return (unsigned short)(r >> 16);
}
__device__ __forceinline__ float bf2f_lo(unsigned int u) { return __uint_as_float(u << 16); }
__device__ __forceinline__ float bf2f_hi(unsigned int u) { return __uint_as_float(u & 0xffff0000u); }

// ---- kernel 1: normalize (blocks 0..2047) + hist/prefix/scatter (block 2048) ----
__global__ __launch_bounds__(256) void k_np(const float* __restrict__ feat,
                                            const int* __restrict__ lab,
                                            unsigned short* __restrict__ fnbf,
                                            int* __restrict__ hist,
                                            int* __restrict__ offs,
                                            int* __restrict__ sorted) {
    if (blockIdx.x < 2048) {
        int wave = threadIdx.x >> 6, lane = threadIdx.x & 63;
        int row  = blockIdx.x * 4 + wave;
        const float4* src = reinterpret_cast<const float4*>(feat + (size_t)row * D_K);
        float4 v = src[lane];
        float ss = v.x * v.x + v.y * v.y + v.z * v.z + v.w * v.w;
#pragma unroll
        for (int m = 1; m < 64; m <<= 1) ss += __shfl_xor(ss, m);
        float rn = 1.0f / sqrtf(ss);
        ushort4 o;
        o.x = f2bf(v.x * rn); o.y = f2bf(v.y * rn);
        o.z = f2bf(v.z * rn); o.w = f2bf(v.w * rn);
        reinterpret_cast<ushort4*>(fnbf + (size_t)row * D_K)[lane] = o;
        return;
    }
    __shared__ int sh_hist[256], sh_scan[256], sh_cur[256];
    int t = threadIdx.x;
    sh_hist[t] = 0;
    __syncthreads();
    for (int i = t; i < B_N; i += 256) {
        int lb = lab[i];
        if (lb >= 0 && lb < NGENE) atomicAdd(&sh_hist[lb], 1);
    }
    __syncthreads();
    int v = sh_hist[t];
    sh_scan[t] = v;
    __syncthreads();
#pragma unroll
    for (int d = 1; d < 256; d <<= 1) {
        int x = (t >= d) ? sh_scan[t - d] : 0;
        __syncthreads();
        sh_scan[t] += x;
        __syncthreads();
    }
    int excl = sh_scan[t] - v;
    sh_cur[t] = excl;
    if (t < NGENE) { hist[t] = v; offs[t] = excl; }
    __syncthreads();
    for (int i = t; i < B_N; i += 256) {
        int lb = lab[i];
        if (lb >= 0 && lb < NGENE) {
            int pos = atomicAdd(&sh_cur[lb], 1);
            sorted[pos] = i;
        }
    }
}

// asm-pinned A-fragment loads (compiler cannot rematerialize or sink)
#define GLOAD8(arr, vo) do {                                                                   \
    asm volatile("global_load_dwordx4 %0, %1, %2 offset:0"   : "=v"(arr[0]) : "v"(vo), "s"(fb)); \
    asm volatile("global_load_dwordx4 %0, %1, %2 offset:64"  : "=v"(arr[1]) : "v"(vo), "s"(fb)); \
    asm volatile("global_load_dwordx4 %0, %1, %2 offset:128" : "=v"(arr[2]) : "v"(vo), "s"(fb)); \
    asm volatile("global_load_dwordx4 %0, %1, %2 offset:192" : "=v"(arr[3]) : "v"(vo), "s"(fb)); \
    asm volatile("global_load_dwordx4 %0, %1, %2 offset:256" : "=v"(arr[4]) : "v"(vo), "s"(fb)); \
    asm volatile("global_load_dwordx4 %0, %1, %2 offset:320" : "=v"(arr[5]) : "v"(vo), "s"(fb)); \
    asm volatile("global_load_dwordx4 %0, %1, %2 offset:384" : "=v"(arr[6]) : "v"(vo), "s"(fb)); \
    asm volatile("global_load_dwordx4 %0, %1, %2 offset:448" : "=v"(arr[7]) : "v"(vo), "s"(fb)); \
} while (0)

// async global->LDS, 16B per lane, zero VGPR result cost
#define GL_LDS16(gp, lp)                                                          \
    __builtin_amdgcn_global_load_lds(                                             \
        (const __attribute__((address_space(1))) unsigned int*)(gp),              \
        (__attribute__((address_space(3))) unsigned int*)(lp), 16, 0, 0)

#define Z4 ((f32x4){0.f, 0.f, 0.f, 0.f})
#define MFMA(A, B, C) __builtin_amdgcn_mfma_f32_16x16x32_bf16(A, B, C, 0, 0, 0)

#define EPI(AC, LS, CS) do {                                    \
    _Pragma("unroll")                                           \
    for (int r = 0; r < 4; ++r) {                               \
        float av = AC[r];                                       \
        LS[r] += __expf(2.0f * av);                             \
        CS += fmaxf(av - 0.05f, 0.f);                           \
    }                                                           \
} while (0)

#define STAGE(BUF) do {                    \
    GL_LDS16(g0, smem_c + (BUF) + st0);    \
    GL_LDS16(g1, smem_c + (BUF) + st1);    \
    GL_LDS16(g2, smem_c + (BUF) + st2);    \
    GL_LDS16(g3, smem_c + (BUF) + st3);    \
    g0 += 16384; g1 += 16384; g2 += 16384; g3 += 16384; \
} while (0)

#define WAIT_VM(n) do { asm volatile("s_waitcnt vmcnt(" #n ")" ::: "memory"); \
                        __builtin_amdgcn_sched_barrier(0); } while (0)

// ---- kernel 2: fused pairwise pass, ring-4 LDS staging with counted vmcnt ----
__global__ __launch_bounds__(256, 2) void k_pairwise(const unsigned short* __restrict__ fnbf,
                                                     float* __restrict__ l_part,
                                                     float* __restrict__ cross_part) {
    __shared__ __align__(16) char smem_c[65536];   // 4 x 16KB B tile ring

    int wave = threadIdx.x >> 6, lane = threadIdx.x & 63;
    int g16 = lane >> 4, l16 = lane & 15;
    int l7 = l16 & 7;
    int rg = blockIdx.x, cwin = blockIdx.y;
    int r0 = rg * 256 + wave * 64;
    const unsigned short* fb = fnbf;

    // A fragments pinned: 4 row-tiles x 8 k-slices = 128 VGPRs
    bf16x8 a0[8], a1[8], a2[8], a3[8];
    unsigned voa = (unsigned)(r0 + l16) * 512u + (unsigned)g16 * 16u;
    GLOAD8(a0, voa); voa += 16u * 512u;
    GLOAD8(a1, voa); voa += 16u * 512u;
    GLOAD8(a2, voa); voa += 16u * 512u;
    GLOAD8(a3, voa);

    // staging source addresses: LDS slot f = col*32 + s receives global chunk
    // c = s ^ (col&7). 4 issues/wave, 1KB each: f = wave*256 + q*64 + lane.
    const char* gwin = (const char*)fnbf + (size_t)cwin * 262144u;  // col-window base
    const char *g0, *g1, *g2, *g3;
    {
        int f0 = wave * 256 + lane;
        int f1 = f0 + 64, f2 = f0 + 128, f3 = f0 + 192;
        int c0 = f0 >> 5, c1 = f1 >> 5, c2 = f2 >> 5, c3 = f3 >> 5;
        g0 = gwin + c0 * 512 + ((f0 & 31) ^ (c0 & 7)) * 16;
        g1 = gwin + c1 * 512 + ((f1 & 31) ^ (c1 & 7)) * 16;
        g2 = gwin + c2 * 512 + ((f2 & 31) ^ (c2 & 7)) * 16;
        g3 = gwin + c3 * 512 + ((f3 & 31) ^ (c3 & 7)) * 16;
    }
    unsigned st0 = wave * 4096u, st1 = st0 + 1024u,
             st2 = st0 + 2048u, st3 = st0 + 3072u;

    // prologue: stage tiles 0,1,2 into bufs 0,1,2; drain A loads (leave 12 staging)
    STAGE(0u);
    STAGE(16384u);
    STAGE(32768u);
    WAIT_VM(12);

    float lsum[4][4] = {};
    float cs0 = 0.f, cs1 = 0.f, cs2 = 0.f, cs3 = 0.f;
    int vb = l16 * 512;

#pragma unroll 1
    for (int st = 0; st < 16; ++st) {
        // tile st was staged 3 steps ago -> this wait is (nearly) free
        if (st < 14)      { WAIT_VM(8); }
        else if (st == 14){ WAIT_VM(4); }
        else              { WAIT_VM(0); }
        __syncthreads();   // publish tile st; frees buf[(st+3)&3] for restage

        if (st < 13) {
            unsigned nb = ((unsigned)(st + 3) & 3u) << 14;
            STAGE(nb);
        }

        const char* base = smem_c + (((unsigned)st & 3u) << 14);
        f32x4 acA0 = Z4, acA1 = Z4, acA2 = Z4, acA3 = Z4;
        f32x4 acB0 = Z4, acB1 = Z4, acB2 = Z4, acB3 = Z4;
#pragma unroll
        for (int ks = 0; ks < 8; ++ks) {
            // chunk (ks*4 + g16) of col l16 lives at slot ((ks*4+g16) ^ l7)
            const char* p = base + (unsigned)(vb + ((((ks << 2) | g16) ^ l7) << 4));
            bf16x8 bv0 = *(const bf16x8*)p;
            bf16x8 bv1 = *(const bf16x8*)(p + 8192);
            acA0 = MFMA(a0[ks], bv0, acA0);
            acA1 = MFMA(a1[ks], bv0, acA1);
            acA2 = MFMA(a2[ks], bv0, acA2);
            acA3 = MFMA(a3[ks], bv0, acA3);
            acB0 = MFMA(a0[ks], bv1, acB0);
            acB1 = MFMA(a1[ks], bv1, acB1);
            acB2 = MFMA(a2[ks], bv1, acB2);
            acB3 = MFMA(a3[ks], bv1, acB3);
        }
        EPI(acA0, lsum[0], cs0); EPI(acA1, lsum[1], cs1);
        EPI(acA2, lsum[2], cs2); EPI(acA3, lsum[3], cs3);
        EPI(acB0, lsum[0], cs0); EPI(acB1, lsum[1], cs1);
        EPI(acB2, lsum[2], cs2); EPI(acB3, lsum[3], cs3);
    }

    // reduce exp-sums across the 16 lanes sharing each output row
#pragma unroll
    for (int t = 0; t < 4; ++t)
#pragma unroll
        for (int r = 0; r < 4; ++r) {
            float v = lsum[t][r];
            v += __shfl_xor(v, 1); v += __shfl_xor(v, 2);
            v += __shfl_xor(v, 4); v += __shfl_xor(v, 8);
            if (l16 == 0)
                l_part[(size_t)cwin * B_N + r0 + t * 16 + g16 * 4 + r] = v;
        }

    // block-reduce half-relu sum
    float c = (cs0 + cs1) + (cs2 + cs3);
#pragma unroll
    for (int m = 1; m < 64; m <<= 1) c += __shfl_xor(c, m);
    __shared__ float shc[4];
    if (lane == 0) shc[wave] = c;
    __syncthreads();
    if (threadIdx.x == 0)
        cross_part[cwin * 32 + rg] = shc[0] + shc[1] + shc[2] + shc[3];
}

// full-row dot from global (fallback path only; 32 x 16B = 512B per row)
__device__ __forceinline__ float dot_g(const uint4* __restrict__ fu, int i, int j) {
    const uint4* pa = fu + (size_t)i * 32;
    const uint4* pb = fu + (size_t)j * 32;
    float d = 0.f;
#pragma unroll
    for (int k = 0; k < 32; ++k) {
        uint4 ua = pa[k], ub = pb[k];
        d = fmaf(bf2f_lo(ua.x), bf2f_lo(ub.x), d);
        d = fmaf(bf2f_hi(ua.x), bf2f_hi(ub.x), d);
        d = fmaf(bf2f_lo(ua.y), bf2f_lo(ub.y), d);
        d = fmaf(bf2f_hi(ua.y), bf2f_hi(ub.y), d);
        d = fmaf(bf2f_lo(ua.z), bf2f_lo(ub.z), d);
        d = fmaf(bf2f_hi(ua.z), bf2f_hi(ub.z), d);
        d = fmaf(bf2f_lo(ua.w), bf2f_lo(ub.w), d);
        d = fmaf(bf2f_hi(ua.w), bf2f_hi(ub.w), d);
    }
    return d;
}

// ---- kernel 3: per-gene Gram matrix via MFMA + corrections + within loss ----
// 4 waves round-robin over 16x16 sim tiles; sims cached in LDS [128][130];
// row-parallel lse pass + pair-parallel softplus pass. No atomics.
__global__ __launch_bounds__(256) void k_within(const unsigned short* __restrict__ fnbf,
                                                const int* __restrict__ hist,
                                                const int* __restrict__ offs,
                                                const int* __restrict__ sorted,
                                                const float* __restrict__ l_part,
                                                float* __restrict__ within_part,
                                                float* __restrict__ cross_corr) {
    int g = blockIdx.x;
    int n = hist[g], start = offs[g];
    int t = threadIdx.x;
    int wave = t >> 6, lane = t & 63;
    int g16 = lane >> 4, l16 = lane & 15;

    __shared__ float sim[128 * 130];   // sim[i][j] at i*130+j (pad -> 2-way banks)
    __shared__ int   rid[MAXN];
    __shared__ float slse[MAXN];
    __shared__ float red[256];

    for (int idx = t; idx < n; idx += 256) rid[idx] = sorted[start + idx];
    __syncthreads();

    float ccor = 0.f, wsum = 0.f;

    if (n <= 128) {
        // ---- Gram matrix via MFMA: tiles (ti,tj), 16x16 each ----
        int NT = (n + 15) >> 4;
        const bf16x8* fv = reinterpret_cast<const bf16x8*>(fnbf);
        for (int tile = wave; tile < NT * NT; tile += 4) {
            int ti = tile / NT, tj = tile - ti * NT;
            int ia = ti * 16 + l16;
            int ib = tj * 16 + l16;
            int ra = rid[ia < n ? ia : (n - 1)];   // clamp: padded results unused
            int rb = rid[ib < n ? ib : (n - 1)];
            f32x4 acc = Z4;
#pragma unroll
            for (int ks = 0; ks < 8; ++ks) {
                bf16x8 av = fv[(size_t)ra * 32 + ks * 4 + g16];
                bf16x8 bv = fv[(size_t)rb * 32 + ks * 4 + g16];
                acc = MFMA(av, bv, acc);
            }
            int si = ti * 16 + g16 * 4;
            int sj = tj * 16 + l16;
#pragma unroll
            for (int r = 0; r < 4; ++r)
                sim[(si + r) * 130 + sj] = acc[r];
        }
        __syncthreads();

        // ---- row pass: lse + cross correction (all j incl diagonal) ----
        for (int i = t; i < n; i += 256) {
            float raw = 0.f;
#pragma unroll
            for (int k = 0; k < 16; ++k) raw += l_part[(size_t)k * B_N + rid[i]];
            const float* srow = &sim[i * 130];
            float esum = 0.f;
            for (int j = 0; j < n; ++j) {
                float s = 2.0f * srow[j];
                esum += __expf(s);
                ccor += fmaxf(s - 0.1f, 0.f);
            }
            slse[i] = __logf(raw - esum);
        }
        __syncthreads();

        // ---- pair pass: softplus, anchor = smaller global row index ----
        int nn = n * n;
        for (int p = t; p < nn; p += 256) {
            int i = p / n, j = p - i * n;
            if (j <= i) continue;
            float s = 2.0f * sim[i * 130 + j];
            int ai = (rid[i] < rid[j]) ? i : j;
            float x = slse[ai] - s;
            wsum += fmaxf(x, 0.f) + log1pf(__expf(-fabsf(x)));
        }
    } else {
        // ---- fallback for absurdly large gene (n > 128): global dots ----
        const uint4* fu = reinterpret_cast<const uint4*>(fnbf);
        for (int i = t; i < n; i += 256) {
            float raw = 0.f;
#pragma unroll
            for (int k = 0; k < 16; ++k) raw += l_part[(size_t)k * B_N + rid[i]];
            float esum = 0.f;
            for (int j = 0; j < n; ++j) {
                float s = 2.0f * dot_g(fu, rid[i], rid[j]);
                esum += __expf(s);
                ccor += fmaxf(s - 0.1f, 0.f);
            }
            slse[i] = __logf(raw - esum);
        }
        __syncthreads();
        int nn = n * n;
        for (int p = t; p < nn; p += 256) {
            int i = p / n, j = p - i * n;
            if (j <= i) continue;
            float s = 2.0f * dot_g(fu, rid[i], rid[j]);
            int ai = (rid[i] < rid[j]) ? i : j;
            float x = slse[ai] - s;
            wsum += fmaxf(x, 0.f) + log1pf(__expf(-fabsf(x)));
        }
    }

    red[t] = wsum;
    __syncthreads();
#pragma unroll
    for (int d2 = 128; d2 > 0; d2 >>= 1) {
        if (t < d2) red[t] += red[t + d2];
        __syncthreads();
    }
    if (t == 0) within_part[g] = red[0];
    __syncthreads();
    red[t] = ccor;
    __syncthreads();
#pragma unroll
    for (int d2 = 128; d2 > 0; d2 >>= 1) {
        if (t < d2) red[t] += red[t + d2];
        __syncthreads();
    }
    if (t == 0) cross_corr[g] = red[0];
}

// ---- kernel 4: final reduction + outputs ----
__global__ __launch_bounds__(256) void k_finalize(const float* __restrict__ cross_part,
                                                  const float* __restrict__ within_part,
                                                  const float* __restrict__ cross_corr,
                                                  const int* __restrict__ hist,
                                                  float* __restrict__ out) {
    __shared__ float shc[256];
    __shared__ float shw[256];
    __shared__ float shk[256];
    __shared__ long long shs[256];
    int t = threadIdx.x;
    float cs = 0.f;
    for (int i = t; i < 512; i += 256) cs += cross_part[i];
    float wv = 0.f, cc = 0.f;
    long long s2 = 0;
    if (t < NGENE) {
        wv = within_part[t];
        cc = cross_corr[t];
        long long h = hist[t];
        s2 = h * h;
    }
    shc[t] = cs; shw[t] = wv; shk[t] = cc; shs[t] = s2;
    __syncthreads();
#pragma unroll
    for (int d = 128; d > 0; d >>= 1) {
        if (t < d) {
            shc[t] += shc[t + d]; shw[t] += shw[t + d];
            shk[t] += shk[t + d]; shs[t] += shs[t + d];
        }
        __syncthreads();
    }
    if (t == 0) {
        long long S  = shs[0];
        long long nw = S - (long long)B_N;
        long long nc = (long long)B_N * (long long)B_N - S;
        float cross_total = 2.0f * shc[0] - shk[0];   // csum was half-relu units
        float cross_loss = (nc > 0) ? (cross_total / (float)(nc > 1 ? nc : 1)) : 0.f;
        float within     = shw[0];
        out[0] = within + 0.5f * cross_loss;
        out[1] = within;
        out[2] = cross_loss;
        out[3] = (float)nw;
        out[4] = (float)nc;
    }
}

extern "C" void kernel_launch(void* const* d_in, const int* in_sizes, int n_in,
                              void* d_out, int out_size, void* d_ws, size_t ws_size,
                              hipStream_t stream) {
    const float* feat = (const float*)d_in[0];
    const int*   lab  = (const int*)d_in[1];
    float* out = (float*)d_out;
    char* ws = (char*)d_ws;

    unsigned short* fnbf = (unsigned short*)(ws + OFF_FNBF);
    float* l_part        = (float*)(ws + OFF_LPART);
    int*   hist          = (int*)(ws + OFF_HIST);
    int*   offs          = (int*)(ws + OFF_OFFS);
    int*   sorted        = (int*)(ws + OFF_SORTED);
    float* cross_part    = (float*)(ws + OFF_CROSSP);
    float* within_part   = (float*)(ws + OFF_WITHINP);
    float* cross_corr    = (float*)(ws + OFF_CCORR);

    k_np<<<2049, 256, 0, stream>>>(feat, lab, fnbf, hist, offs, sorted);
    k_pairwise<<<dim3(32, 16), 256, 0, stream>>>(fnbf, l_part, cross_part);
    k_within<<<NGENE, 256, 0, stream>>>(fnbf, hist, offs, sorted, l_part, within_part, cross_corr);
    k_finalize<<<1, 256, 0, stream>>>(cross_part, within_part, cross_corr, hist, out);
}

// Round 11
// 94.234 us; speedup vs baseline: 3.1463x; 1.0065x over previous
//
#include <hip/hip_runtime.h>
#include <math.h>

#define B_N   8192
#define D_K   256
#define NGENE 200
#define MAXN  512

typedef short  bf16x8 __attribute__((ext_vector_type(8)));
typedef float  f32x4  __attribute__((ext_vector_type(4)));

// ---- workspace layout (bytes), total 4,757,504 (proven size) ----
#define OFF_FNBF    0u          // 8192*256*2 = 4194304
#define OFF_LPART   4194304u    // f32 [16][8192] = 524288
#define OFF_HIST    4718592u    // 256*4
#define OFF_OFFS    4719616u    // 256*4
#define OFF_SORTED  4720640u    // 8192*4
#define OFF_CROSSP  4753408u    // 512*4
#define OFF_WITHINP 4755456u    // 256*4
#define OFF_CCORR   4756480u    // 256*4

__device__ __forceinline__ unsigned short f2bf(float f) {
    unsigned int u = __float_as_uint(f);
    unsigned int r = u + 0x7fffu + ((u >> 16) & 1u);
    return (unsigned short)(r >> 16);
}
__device__ __forceinline__ float bf2f_lo(unsigned int u) { return __uint_as_float(u << 16); }
__device__ __forceinline__ float bf2f_hi(unsigned int u) { return __uint_as_float(u & 0xffff0000u); }

// ---- kernel 1: normalize (blocks 0..2047) + hist/prefix/scatter (block 2048) ----
__global__ __launch_bounds__(256) void k_np(const float* __restrict__ feat,
                                            const int* __restrict__ lab,
                                            unsigned short* __restrict__ fnbf,
                                            int* __restrict__ hist,
                                            int* __restrict__ offs,
                                            int* __restrict__ sorted) {
    if (blockIdx.x < 2048) {
        int wave = threadIdx.x >> 6, lane = threadIdx.x & 63;
        int row  = blockIdx.x * 4 + wave;
        const float4* src = reinterpret_cast<const float4*>(feat + (size_t)row * D_K);
        float4 v = src[lane];
        float ss = v.x * v.x + v.y * v.y + v.z * v.z + v.w * v.w;
#pragma unroll
        for (int m = 1; m < 64; m <<= 1) ss += __shfl_xor(ss, m);
        float rn = 1.0f / sqrtf(ss);
        ushort4 o;
        o.x = f2bf(v.x * rn); o.y = f2bf(v.y * rn);
        o.z = f2bf(v.z * rn); o.w = f2bf(v.w * rn);
        reinterpret_cast<ushort4*>(fnbf + (size_t)row * D_K)[lane] = o;
        return;
    }
    __shared__ int sh_hist[256], sh_scan[256], sh_cur[256];
    int t = threadIdx.x;
    sh_hist[t] = 0;
    __syncthreads();
    for (int i = t; i < B_N; i += 256) {
        int lb = lab[i];
        if (lb >= 0 && lb < NGENE) atomicAdd(&sh_hist[lb], 1);
    }
    __syncthreads();
    int v = sh_hist[t];
    sh_scan[t] = v;
    __syncthreads();
#pragma unroll
    for (int d = 1; d < 256; d <<= 1) {
        int x = (t >= d) ? sh_scan[t - d] : 0;
        __syncthreads();
        sh_scan[t] += x;
        __syncthreads();
    }
    int excl = sh_scan[t] - v;
    sh_cur[t] = excl;
    if (t < NGENE) { hist[t] = v; offs[t] = excl; }
    __syncthreads();
    for (int i = t; i < B_N; i += 256) {
        int lb = lab[i];
        if (lb >= 0 && lb < NGENE) {
            int pos = atomicAdd(&sh_cur[lb], 1);
            sorted[pos] = i;
        }
    }
}

// asm-pinned A-fragment loads (compiler cannot rematerialize or sink)
#define GLOAD8(arr, vo) do {                                                                   \
    asm volatile("global_load_dwordx4 %0, %1, %2 offset:0"   : "=v"(arr[0]) : "v"(vo), "s"(fb)); \
    asm volatile("global_load_dwordx4 %0, %1, %2 offset:64"  : "=v"(arr[1]) : "v"(vo), "s"(fb)); \
    asm volatile("global_load_dwordx4 %0, %1, %2 offset:128" : "=v"(arr[2]) : "v"(vo), "s"(fb)); \
    asm volatile("global_load_dwordx4 %0, %1, %2 offset:192" : "=v"(arr[3]) : "v"(vo), "s"(fb)); \
    asm volatile("global_load_dwordx4 %0, %1, %2 offset:256" : "=v"(arr[4]) : "v"(vo), "s"(fb)); \
    asm volatile("global_load_dwordx4 %0, %1, %2 offset:320" : "=v"(arr[5]) : "v"(vo), "s"(fb)); \
    asm volatile("global_load_dwordx4 %0, %1, %2 offset:384" : "=v"(arr[6]) : "v"(vo), "s"(fb)); \
    asm volatile("global_load_dwordx4 %0, %1, %2 offset:448" : "=v"(arr[7]) : "v"(vo), "s"(fb)); \
} while (0)

// async global->LDS, 16B per lane, zero VGPR result cost
#define GL_LDS16(gp, lp)                                                          \
    __builtin_amdgcn_global_load_lds(                                             \
        (const __attribute__((address_space(1))) unsigned int*)(gp),              \
        (__attribute__((address_space(3))) unsigned int*)(lp), 16, 0, 0)

#define Z4 ((f32x4){0.f, 0.f, 0.f, 0.f})
#define MFMA(A, B, C) __builtin_amdgcn_mfma_f32_16x16x32_bf16(A, B, C, 0, 0, 0)

#define EPI(AC, LS, CS) do {                                    \
    _Pragma("unroll")                                           \
    for (int r = 0; r < 4; ++r) {                               \
        float av = AC[r];                                       \
        LS[r] += __expf(2.0f * av);                             \
        CS += fmaxf(av - 0.05f, 0.f);                           \
    }                                                           \
} while (0)

#define STAGE(BUF) do {                    \
    GL_LDS16(g0, smem_c + (BUF) + st0);    \
    GL_LDS16(g1, smem_c + (BUF) + st1);    \
    GL_LDS16(g2, smem_c + (BUF) + st2);    \
    GL_LDS16(g3, smem_c + (BUF) + st3);    \
    g0 += 16384; g1 += 16384; g2 += 16384; g3 += 16384; \
} while (0)

#define WAIT_VM(n) do { asm volatile("s_waitcnt vmcnt(" #n ")" ::: "memory"); \
                        __builtin_amdgcn_sched_barrier(0); } while (0)

// ---- kernel 2: fused pairwise pass, ring-4 LDS staging, counted vmcnt + RAW barrier ----
// (raw s_barrier: no implicit vmcnt(0) drain -> staging loads stay in flight across steps)
__global__ __launch_bounds__(256, 2) void k_pairwise(const unsigned short* __restrict__ fnbf,
                                                     float* __restrict__ l_part,
                                                     float* __restrict__ cross_part) {
    __shared__ __align__(16) char smem_c[65536];   // 4 x 16KB B tile ring

    int wave = threadIdx.x >> 6, lane = threadIdx.x & 63;
    int g16 = lane >> 4, l16 = lane & 15;
    int l7 = l16 & 7;
    int rg = blockIdx.x, cwin = blockIdx.y;
    int r0 = rg * 256 + wave * 64;
    const unsigned short* fb = fnbf;

    // A fragments pinned: 4 row-tiles x 8 k-slices = 128 VGPRs
    bf16x8 a0[8], a1[8], a2[8], a3[8];
    unsigned voa = (unsigned)(r0 + l16) * 512u + (unsigned)g16 * 16u;
    GLOAD8(a0, voa); voa += 16u * 512u;
    GLOAD8(a1, voa); voa += 16u * 512u;
    GLOAD8(a2, voa); voa += 16u * 512u;
    GLOAD8(a3, voa);

    // staging source addresses: LDS slot f = col*32 + s receives global chunk
    // c = s ^ (col&7). 4 issues/wave, 1KB each: f = wave*256 + q*64 + lane.
    const char* gwin = (const char*)fnbf + (size_t)cwin * 262144u;  // col-window base
    const char *g0, *g1, *g2, *g3;
    {
        int f0 = wave * 256 + lane;
        int f1 = f0 + 64, f2 = f0 + 128, f3 = f0 + 192;
        int c0 = f0 >> 5, c1 = f1 >> 5, c2 = f2 >> 5, c3 = f3 >> 5;
        g0 = gwin + c0 * 512 + ((f0 & 31) ^ (c0 & 7)) * 16;
        g1 = gwin + c1 * 512 + ((f1 & 31) ^ (c1 & 7)) * 16;
        g2 = gwin + c2 * 512 + ((f2 & 31) ^ (c2 & 7)) * 16;
        g3 = gwin + c3 * 512 + ((f3 & 31) ^ (c3 & 7)) * 16;
    }
    unsigned st0 = wave * 4096u, st1 = st0 + 1024u,
             st2 = st0 + 2048u, st3 = st0 + 3072u;

    // prologue: stage tiles 0,1,2 into bufs 0,1,2; drain A loads (leave 12 staging)
    STAGE(0u);
    STAGE(16384u);
    STAGE(32768u);
    WAIT_VM(12);

    float lsum[4][4] = {};
    float cs0 = 0.f, cs1 = 0.f, cs2 = 0.f, cs3 = 0.f;
    int vb = l16 * 512;

#pragma unroll 1
    for (int st = 0; st < 16; ++st) {
        // tile st was staged 3 steps ago -> counted wait is (nearly) free
        if (st < 14)      { WAIT_VM(8); }
        else if (st == 14){ WAIT_VM(4); }
        else              { WAIT_VM(0); }
        __builtin_amdgcn_s_barrier();   // raw barrier: NO implicit vmcnt drain

        if (st < 13) {
            unsigned nb = ((unsigned)(st + 3) & 3u) << 14;
            STAGE(nb);
        }

        const char* base = smem_c + (((unsigned)st & 3u) << 14);
        f32x4 acA0 = Z4, acA1 = Z4, acA2 = Z4, acA3 = Z4;
        f32x4 acB0 = Z4, acB1 = Z4, acB2 = Z4, acB3 = Z4;
#pragma unroll
        for (int ks = 0; ks < 8; ++ks) {
            // chunk (ks*4 + g16) of col l16 lives at slot ((ks*4+g16) ^ l7)
            const char* p = base + (unsigned)(vb + ((((ks << 2) | g16) ^ l7) << 4));
            bf16x8 bv0 = *(const bf16x8*)p;
            bf16x8 bv1 = *(const bf16x8*)(p + 8192);
            acA0 = MFMA(a0[ks], bv0, acA0);
            acA1 = MFMA(a1[ks], bv0, acA1);
            acA2 = MFMA(a2[ks], bv0, acA2);
            acA3 = MFMA(a3[ks], bv0, acA3);
            acB0 = MFMA(a0[ks], bv1, acB0);
            acB1 = MFMA(a1[ks], bv1, acB1);
            acB2 = MFMA(a2[ks], bv1, acB2);
            acB3 = MFMA(a3[ks], bv1, acB3);
        }
        EPI(acA0, lsum[0], cs0); EPI(acA1, lsum[1], cs1);
        EPI(acA2, lsum[2], cs2); EPI(acA3, lsum[3], cs3);
        EPI(acB0, lsum[0], cs0); EPI(acB1, lsum[1], cs1);
        EPI(acB2, lsum[2], cs2); EPI(acB3, lsum[3], cs3);
    }

    // reduce exp-sums across the 16 lanes sharing each output row
#pragma unroll
    for (int t = 0; t < 4; ++t)
#pragma unroll
        for (int r = 0; r < 4; ++r) {
            float v = lsum[t][r];
            v += __shfl_xor(v, 1); v += __shfl_xor(v, 2);
            v += __shfl_xor(v, 4); v += __shfl_xor(v, 8);
            if (l16 == 0)
                l_part[(size_t)cwin * B_N + r0 + t * 16 + g16 * 4 + r] = v;
        }

    // block-reduce half-relu sum
    float c = (cs0 + cs1) + (cs2 + cs3);
#pragma unroll
    for (int m = 1; m < 64; m <<= 1) c += __shfl_xor(c, m);
    __shared__ float shc[4];
    if (lane == 0) shc[wave] = c;
    __syncthreads();
    if (threadIdx.x == 0)
        cross_part[cwin * 32 + rg] = shc[0] + shc[1] + shc[2] + shc[3];
}

// full-row dot from global (fallback path only; 32 x 16B = 512B per row)
__device__ __forceinline__ float dot_g(const uint4* __restrict__ fu, int i, int j) {
    const uint4* pa = fu + (size_t)i * 32;
    const uint4* pb = fu + (size_t)j * 32;
    float d = 0.f;
#pragma unroll
    for (int k = 0; k < 32; ++k) {
        uint4 ua = pa[k], ub = pb[k];
        d = fmaf(bf2f_lo(ua.x), bf2f_lo(ub.x), d);
        d = fmaf(bf2f_hi(ua.x), bf2f_hi(ub.x), d);
        d = fmaf(bf2f_lo(ua.y), bf2f_lo(ub.y), d);
        d = fmaf(bf2f_hi(ua.y), bf2f_hi(ub.y), d);
        d = fmaf(bf2f_lo(ua.z), bf2f_lo(ub.z), d);
        d = fmaf(bf2f_hi(ua.z), bf2f_hi(ub.z), d);
        d = fmaf(bf2f_lo(ua.w), bf2f_lo(ub.w), d);
        d = fmaf(bf2f_hi(ua.w), bf2f_hi(ub.w), d);
    }
    return d;
}

// ---- kernel 3: per-gene Gram matrix via MFMA + corrections + within loss ----
__global__ __launch_bounds__(256) void k_within(const unsigned short* __restrict__ fnbf,
                                                const int* __restrict__ hist,
                                                const int* __restrict__ offs,
                                                const int* __restrict__ sorted,
                                                const float* __restrict__ l_part,
                                                float* __restrict__ within_part,
                                                float* __restrict__ cross_corr) {
    int g = blockIdx.x;
    int n = hist[g], start = offs[g];
    int t = threadIdx.x;
    int wave = t >> 6, lane = t & 63;
    int g16 = lane >> 4, l16 = lane & 15;

    __shared__ float sim[128 * 130];   // sim[i][j] at i*130+j (pad -> 2-way banks)
    __shared__ int   rid[MAXN];
    __shared__ float slse[MAXN];
    __shared__ float red[256];

    for (int idx = t; idx < n; idx += 256) rid[idx] = sorted[start + idx];
    __syncthreads();

    float ccor = 0.f, wsum = 0.f;

    if (n <= 128) {
        // ---- Gram matrix via MFMA: tiles (ti,tj), 16x16 each ----
        int NT = (n + 15) >> 4;
        const bf16x8* fv = reinterpret_cast<const bf16x8*>(fnbf);
        for (int tile = wave; tile < NT * NT; tile += 4) {
            int ti = tile / NT, tj = tile - ti * NT;
            int ia = ti * 16 + l16;
            int ib = tj * 16 + l16;
            int ra = rid[ia < n ? ia : (n - 1)];   // clamp: padded results unused
            int rb = rid[ib < n ? ib : (n - 1)];
            f32x4 acc = Z4;
#pragma unroll
            for (int ks = 0; ks < 8; ++ks) {
                bf16x8 av = fv[(size_t)ra * 32 + ks * 4 + g16];
                bf16x8 bv = fv[(size_t)rb * 32 + ks * 4 + g16];
                acc = MFMA(av, bv, acc);
            }
            int si = ti * 16 + g16 * 4;
            int sj = tj * 16 + l16;
#pragma unroll
            for (int r = 0; r < 4; ++r)
                sim[(si + r) * 130 + sj] = acc[r];
        }
        __syncthreads();

        // ---- row pass: lse + cross correction (all j incl diagonal) ----
        for (int i = t; i < n; i += 256) {
            float raw = 0.f;
#pragma unroll
            for (int k = 0; k < 16; ++k) raw += l_part[(size_t)k * B_N + rid[i]];
            const float* srow = &sim[i * 130];
            float esum = 0.f;
            for (int j = 0; j < n; ++j) {
                float s = 2.0f * srow[j];
                esum += __expf(s);
                ccor += fmaxf(s - 0.1f, 0.f);
            }
            slse[i] = __logf(raw - esum);
        }
        __syncthreads();

        // ---- pair pass: softplus, anchor = smaller global row index ----
        int nn = n * n;
        for (int p = t; p < nn; p += 256) {
            int i = p / n, j = p - i * n;
            if (j <= i) continue;
            float s = 2.0f * sim[i * 130 + j];
            int ai = (rid[i] < rid[j]) ? i : j;
            float x = slse[ai] - s;
            wsum += fmaxf(x, 0.f) + log1pf(__expf(-fabsf(x)));
        }
    } else {
        // ---- fallback for absurdly large gene (n > 128): global dots ----
        const uint4* fu = reinterpret_cast<const uint4*>(fnbf);
        for (int i = t; i < n; i += 256) {
            float raw = 0.f;
#pragma unroll
            for (int k = 0; k < 16; ++k) raw += l_part[(size_t)k * B_N + rid[i]];
            float esum = 0.f;
            for (int j = 0; j < n; ++j) {
                float s = 2.0f * dot_g(fu, rid[i], rid[j]);
                esum += __expf(s);
                ccor += fmaxf(s - 0.1f, 0.f);
            }
            slse[i] = __logf(raw - esum);
        }
        __syncthreads();
        int nn = n * n;
        for (int p = t; p < nn; p += 256) {
            int i = p / n, j = p - i * n;
            if (j <= i) continue;
            float s = 2.0f * dot_g(fu, rid[i], rid[j]);
            int ai = (rid[i] < rid[j]) ? i : j;
            float x = slse[ai] - s;
            wsum += fmaxf(x, 0.f) + log1pf(__expf(-fabsf(x)));
        }
    }

    red[t] = wsum;
    __syncthreads();
#pragma unroll
    for (int d2 = 128; d2 > 0; d2 >>= 1) {
        if (t < d2) red[t] += red[t + d2];
        __syncthreads();
    }
    if (t == 0) within_part[g] = red[0];
    __syncthreads();
    red[t] = ccor;
    __syncthreads();
#pragma unroll
    for (int d2 = 128; d2 > 0; d2 >>= 1) {
        if (t < d2) red[t] += red[t + d2];
        __syncthreads();
    }
    if (t == 0) cross_corr[g] = red[0];
}

// ---- kernel 4: final reduction + outputs ----
__global__ __launch_bounds__(256) void k_finalize(const float* __restrict__ cross_part,
                                                  const float* __restrict__ within_part,
                                                  const float* __restrict__ cross_corr,
                                                  const int* __restrict__ hist,
                                                  float* __restrict__ out) {
    __shared__ float shc[256];
    __shared__ float shw[256];
    __shared__ float shk[256];
    __shared__ long long shs[256];
    int t = threadIdx.x;
    float cs = 0.f;
    for (int i = t; i < 512; i += 256) cs += cross_part[i];
    float wv = 0.f, cc = 0.f;
    long long s2 = 0;
    if (t < NGENE) {
        wv = within_part[t];
        cc = cross_corr[t];
        long long h = hist[t];
        s2 = h * h;
    }
    shc[t] = cs; shw[t] = wv; shk[t] = cc; shs[t] = s2;
    __syncthreads();
#pragma unroll
    for (int d = 128; d > 0; d >>= 1) {
        if (t < d) {
            shc[t] += shc[t + d]; shw[t] += shw[t + d];
            shk[t] += shk[t + d]; shs[t] += shs[t + d];
        }
        __syncthreads();
    }
    if (t == 0) {
        long long S  = shs[0];
        long long nw = S - (long long)B_N;
        long long nc = (long long)B_N * (long long)B_N - S;
        float cross_total = 2.0f * shc[0] - shk[0];   // csum was half-relu units
        float cross_loss = (nc > 0) ? (cross_total / (float)(nc > 1 ? nc : 1)) : 0.f;
        float within     = shw[0];
        out[0] = within + 0.5f * cross_loss;
        out[1] = within;
        out[2] = cross_loss;
        out[3] = (float)nw;
        out[4] = (float)nc;
    }
}

extern "C" void kernel_launch(void* const* d_in, const int* in_sizes, int n_in,
                              void* d_out, int out_size, void* d_ws, size_t ws_size,
                              hipStream_t stream) {
    const float* feat = (const float*)d_in[0];
    const int*   lab  = (const int*)d_in[1];
    float* out = (float*)d_out;
    char* ws = (char*)d_ws;

    unsigned short* fnbf = (unsigned short*)(ws + OFF_FNBF);
    float* l_part        = (float*)(ws + OFF_LPART);
    int*   hist          = (int*)(ws + OFF_HIST);
    int*   offs          = (int*)(ws + OFF_OFFS);
    int*   sorted        = (int*)(ws + OFF_SORTED);
    float* cross_part    = (float*)(ws + OFF_CROSSP);
    float* within_part   = (float*)(ws + OFF_WITHINP);
    float* cross_corr    = (float*)(ws + OFF_CCORR);

    k_np<<<2049, 256, 0, stream>>>(feat, lab, fnbf, hist, offs, sorted);
    k_pairwise<<<dim3(32, 16), 256, 0, stream>>>(fnbf, l_part, cross_part);
    k_within<<<NGENE, 256, 0, stream>>>(fnbf, hist, offs, sorted, l_part, within_part, cross_corr);
    k_finalize<<<1, 256, 0, stream>>>(cross_part, within_part, cross_corr, hist, out);
}